// Round 4
// baseline (3058.801 us; speedup 1.0000x reference)
//
#include <hip/hip_runtime.h>

#define NN 100000
#define FF 500
#define HH 64
#define CC 40
#define EE 1000000
#define NB 782            // buckets per scale: ceil(100000/128)
#define NBK 2346          // 3*NB

// ---------------------------------------------------------------------------
// GEMM: C[N][64] = (opt relu)(A[N][K]) @ B[K][64] + bias[64]
// ---------------------------------------------------------------------------
template <int K, bool RELU>
__global__ __launch_bounds__(256) void gemm_n64(
    const float* __restrict__ A,
    const float* __restrict__ B,
    const float* __restrict__ bias,
    float* __restrict__ C,
    int nrows)
{
    __shared__ float As[32][68];
    __shared__ float Bs[32][64];

    const int tid = threadIdx.x;
    const int tx = tid & 15;
    const int ty = tid >> 4;
    const int row0 = blockIdx.x * 64;

    float acc[4][4] = {{0.f, 0.f, 0.f, 0.f}, {0.f, 0.f, 0.f, 0.f},
                       {0.f, 0.f, 0.f, 0.f}, {0.f, 0.f, 0.f, 0.f}};

    const int r = tid >> 2;
    const int koff = (tid & 3) * 8;
    const bool rowok = (row0 + r) < nrows;

    for (int k0 = 0; k0 < K; k0 += 32) {
        float av[8];
        const float* ap = A + (size_t)(row0 + r) * K + (k0 + koff);
        if (rowok && ((K % 32 == 0) || (k0 + 32 <= K))) {
            float4 v0 = *(const float4*)(ap);
            float4 v1 = *(const float4*)(ap + 4);
            av[0] = v0.x; av[1] = v0.y; av[2] = v0.z; av[3] = v0.w;
            av[4] = v1.x; av[5] = v1.y; av[6] = v1.z; av[7] = v1.w;
        } else {
            #pragma unroll
            for (int j = 0; j < 8; ++j) {
                int kk = k0 + koff + j;
                av[j] = (rowok && kk < K) ? ap[j] : 0.f;
            }
        }
        if (RELU) {
            #pragma unroll
            for (int j = 0; j < 8; ++j) av[j] = fmaxf(av[j], 0.f);
        }
        #pragma unroll
        for (int j = 0; j < 8; ++j) As[koff + j][r] = av[j];

        {
            int flat = tid * 8;
            int kk = flat >> 6;
            int c = flat & 63;
            float4 b0, b1v;
            if (k0 + kk < K) {
                b0 = *(const float4*)(B + (size_t)(k0 + kk) * 64 + c);
                b1v = *(const float4*)(B + (size_t)(k0 + kk) * 64 + c + 4);
            } else {
                b0 = make_float4(0.f, 0.f, 0.f, 0.f);
                b1v = b0;
            }
            *(float4*)&Bs[kk][c] = b0;
            *(float4*)&Bs[kk][c + 4] = b1v;
        }
        __syncthreads();

        #pragma unroll
        for (int k = 0; k < 32; ++k) {
            float4 a = *(const float4*)&As[k][ty * 4];
            float4 b = *(const float4*)&Bs[k][tx * 4];
            acc[0][0] = fmaf(a.x, b.x, acc[0][0]);
            acc[0][1] = fmaf(a.x, b.y, acc[0][1]);
            acc[0][2] = fmaf(a.x, b.z, acc[0][2]);
            acc[0][3] = fmaf(a.x, b.w, acc[0][3]);
            acc[1][0] = fmaf(a.y, b.x, acc[1][0]);
            acc[1][1] = fmaf(a.y, b.y, acc[1][1]);
            acc[1][2] = fmaf(a.y, b.z, acc[1][2]);
            acc[1][3] = fmaf(a.y, b.w, acc[1][3]);
            acc[2][0] = fmaf(a.z, b.x, acc[2][0]);
            acc[2][1] = fmaf(a.z, b.y, acc[2][1]);
            acc[2][2] = fmaf(a.z, b.z, acc[2][2]);
            acc[2][3] = fmaf(a.z, b.w, acc[2][3]);
            acc[3][0] = fmaf(a.w, b.x, acc[3][0]);
            acc[3][1] = fmaf(a.w, b.y, acc[3][1]);
            acc[3][2] = fmaf(a.w, b.z, acc[3][2]);
            acc[3][3] = fmaf(a.w, b.w, acc[3][3]);
        }
        __syncthreads();
    }

    float4 bv = *(const float4*)(bias + tx * 4);
    #pragma unroll
    for (int i = 0; i < 4; ++i) {
        int rr = row0 + ty * 4 + i;
        if (rr < nrows) {
            float4 o;
            o.x = acc[i][0] + bv.x;
            o.y = acc[i][1] + bv.y;
            o.z = acc[i][2] + bv.z;
            o.w = acc[i][3] + bv.w;
            *(float4*)(C + (size_t)rr * 64 + tx * 4) = o;
        }
    }
}

// ---------------------------------------------------------------------------
// Bucket histogram: bucket = (scale, dst>>7). LDS-aggregated.
// ---------------------------------------------------------------------------
__global__ __launch_bounds__(256) void hist_bucket(
    const int* __restrict__ ei1, const int* __restrict__ ei2,
    const int* __restrict__ ei3, int* __restrict__ gcnt)
{
    __shared__ int lc[NBK];
    for (int j = threadIdx.x; j < NBK; j += 256) lc[j] = 0;
    __syncthreads();
    for (int i = blockIdx.x * 256 + threadIdx.x; i < 3 * EE;
         i += gridDim.x * 256) {
        int s = i / EE;
        int e = i - s * EE;
        const int* ei = (s == 0) ? ei1 : (s == 1) ? ei2 : ei3;
        int dst = ei[EE + e];
        atomicAdd(&lc[s * NB + (dst >> 7)], 1);
    }
    __syncthreads();
    for (int j = threadIdx.x; j < NBK; j += 256)
        if (lc[j]) atomicAdd(&gcnt[j], lc[j]);
}

// ---------------------------------------------------------------------------
// Single-block exclusive scan over NBK counters (chunks of 1024 w/ carry).
// ---------------------------------------------------------------------------
__global__ __launch_bounds__(1024) void scan_buckets(
    const int* __restrict__ cnt, int* __restrict__ off, int* __restrict__ cur)
{
    __shared__ int sh[1024];
    __shared__ int carry;
    if (threadIdx.x == 0) carry = 0;
    __syncthreads();
    for (int base = 0; base < NBK; base += 1024) {
        int i = base + threadIdx.x;
        int v = (i < NBK) ? cnt[i] : 0;
        sh[threadIdx.x] = v;
        __syncthreads();
        #pragma unroll
        for (int o = 1; o < 1024; o <<= 1) {
            int add = (threadIdx.x >= o) ? sh[threadIdx.x - o] : 0;
            __syncthreads();
            sh[threadIdx.x] += add;
            __syncthreads();
        }
        int excl = sh[threadIdx.x] - v + carry;
        if (i < NBK) { off[i] = excl; cur[i] = excl; }
        __syncthreads();
        if (threadIdx.x == 1023) carry += sh[1023];
        __syncthreads();
    }
    if (threadIdx.x == 0) off[NBK] = 3 * EE;
}

// ---------------------------------------------------------------------------
// Bucket scatter: record = (src | dst_local<<17, weight). Write frontier is
// 2346 cursors -> L2-resident -> full-line merges.
// ---------------------------------------------------------------------------
__global__ __launch_bounds__(256) void bucket_scatter(
    const int* __restrict__ ei1, const float* __restrict__ ea1,
    const int* __restrict__ ei2, const float* __restrict__ ea2,
    const int* __restrict__ ei3, const float* __restrict__ ea3,
    int* __restrict__ cur, int2* __restrict__ brec)
{
    int i = blockIdx.x * 256 + threadIdx.x;
    if (i >= 3 * EE) return;
    int s = i / EE;
    int e = i - s * EE;
    const int* ei = (s == 0) ? ei1 : (s == 1) ? ei2 : ei3;
    const float* ea = (s == 0) ? ea1 : (s == 1) ? ea2 : ea3;
    int src = ei[e];
    int dst = ei[EE + e];
    float w = ea[e];
    int pos = atomicAdd(&cur[s * NB + (dst >> 7)], 1);
    brec[pos] = make_int2(src | ((dst & 127) << 17), __float_as_int(w));
}

// ---------------------------------------------------------------------------
// Fused UFG: one block per (scale, bucket). acc[128][64] in LDS; 4 waves
// stream the bucket's records with 4-deep ILP; ds_add_f32 accumulate;
// filter applied in epilogue; coalesced row writes (covers all of agg,
// so no memset needed).
// ---------------------------------------------------------------------------
__global__ __launch_bounds__(256) void ufg_bucket(
    const float* __restrict__ h,          // [N][64]
    const int* __restrict__ off,          // [NBK+1]
    const int2* __restrict__ brec,        // [3E]
    const float* __restrict__ f1, const float* __restrict__ f2,
    const float* __restrict__ f3,
    float* __restrict__ agg)              // [N][192]
{
    __shared__ float sacc[128 * 64];
    const int lane = threadIdx.x & 63;
    const int wv = threadIdx.x >> 6;
    const int bk = blockIdx.x;            // s*NB + b
    const int s = bk / NB;
    const int b = bk - s * NB;
    const int n0 = b << 7;

    for (int j = threadIdx.x; j < 128 * 64; j += 256) sacc[j] = 0.f;
    __syncthreads();

    const int beg = off[bk];
    const int end = off[bk + 1];
    const int chunk = (end - beg + 3) >> 2;
    int p = beg + wv * chunk;
    int pe = p + chunk;
    if (pe > end) pe = end;
    const float* hl = h + lane;

    for (; p + 4 <= pe; p += 4) {
        int2 r0 = brec[p + 0];
        int2 r1 = brec[p + 1];
        int2 r2 = brec[p + 2];
        int2 r3 = brec[p + 3];
        float v0 = hl[(size_t)(r0.x & 0x1FFFF) * 64];
        float v1 = hl[(size_t)(r1.x & 0x1FFFF) * 64];
        float v2 = hl[(size_t)(r2.x & 0x1FFFF) * 64];
        float v3 = hl[(size_t)(r3.x & 0x1FFFF) * 64];
        atomicAdd(&sacc[((r0.x >> 17) & 127) * 64 + lane],
                  __int_as_float(r0.y) * v0);
        atomicAdd(&sacc[((r1.x >> 17) & 127) * 64 + lane],
                  __int_as_float(r1.y) * v1);
        atomicAdd(&sacc[((r2.x >> 17) & 127) * 64 + lane],
                  __int_as_float(r2.y) * v2);
        atomicAdd(&sacc[((r3.x >> 17) & 127) * 64 + lane],
                  __int_as_float(r3.y) * v3);
    }
    for (; p < pe; ++p) {
        int2 r = brec[p];
        float v = hl[(size_t)(r.x & 0x1FFFF) * 64];
        atomicAdd(&sacc[((r.x >> 17) & 127) * 64 + lane],
                  __int_as_float(r.y) * v);
    }
    __syncthreads();

    const float* fp = (s == 0) ? f1 : (s == 1) ? f2 : f3;
    const float fv = fp[lane];
    for (int dl = wv; dl < 128; dl += 4) {
        int n = n0 + dl;
        if (n < NN)
            agg[(size_t)n * 192 + s * 64 + lane] = sacc[dl * 64 + lane] * fv;
    }
}

// ---------------------------------------------------------------------------
// GEMM3 + log_softmax
// ---------------------------------------------------------------------------
__global__ __launch_bounds__(256) void gemm_softmax(
    const float* __restrict__ A, const float* __restrict__ W,
    const float* __restrict__ bias, float* __restrict__ out)
{
    __shared__ float Ws[192 * 40];
    for (int i = threadIdx.x; i < 192 * 40; i += 256) Ws[i] = W[i];
    __syncthreads();

    const int lane = threadIdx.x & 63;
    const int wv = threadIdx.x >> 6;
    const bool act = lane < 40;
    const int cl = act ? lane : 39;

    for (int row = blockIdx.x * 4 + wv; row < NN; row += gridDim.x * 4) {
        const float* a = A + (size_t)row * 192;
        float acc = bias[cl];
        #pragma unroll 8
        for (int k0 = 0; k0 < 192; k0 += 4) {
            float4 av = *(const float4*)(a + k0);
            av.x = fmaxf(av.x, 0.f);
            av.y = fmaxf(av.y, 0.f);
            av.z = fmaxf(av.z, 0.f);
            av.w = fmaxf(av.w, 0.f);
            acc = fmaf(av.x, Ws[(k0 + 0) * 40 + cl], acc);
            acc = fmaf(av.y, Ws[(k0 + 1) * 40 + cl], acc);
            acc = fmaf(av.z, Ws[(k0 + 2) * 40 + cl], acc);
            acc = fmaf(av.w, Ws[(k0 + 3) * 40 + cl], acc);
        }
        float v = act ? acc : -1e30f;
        #pragma unroll
        for (int off = 32; off > 0; off >>= 1)
            v = fmaxf(v, __shfl_xor(v, off, 64));
        float ex = act ? __expf(acc - v) : 0.f;
        float s = ex;
        #pragma unroll
        for (int off = 32; off > 0; off >>= 1)
            s += __shfl_xor(s, off, 64);
        if (act) out[(size_t)row * 40 + lane] = acc - v - __logf(s);
    }
}

// ---------------------------------------------------------------------------
extern "C" void kernel_launch(void* const* d_in, const int* in_sizes, int n_in,
                              void* d_out, int out_size, void* d_ws, size_t ws_size,
                              hipStream_t stream)
{
    const float* x    = (const float*)d_in[0];
    const int*   ei1  = (const int*)d_in[1];
    const float* ea1  = (const float*)d_in[2];
    const int*   ei2  = (const int*)d_in[3];
    const float* ea2  = (const float*)d_in[4];
    const int*   ei3  = (const int*)d_in[5];
    const float* ea3  = (const float*)d_in[6];
    const float* W1   = (const float*)d_in[7];
    const float* b1   = (const float*)d_in[8];
    const float* f1_1 = (const float*)d_in[9];
    const float* f2_1 = (const float*)d_in[10];
    const float* f1_2 = (const float*)d_in[11];
    const float* f2_2 = (const float*)d_in[12];
    const float* f1_3 = (const float*)d_in[13];
    const float* f2_3 = (const float*)d_in[14];
    const float* Wm2  = (const float*)d_in[15];
    const float* bm2  = (const float*)d_in[16];
    const float* Wm1  = (const float*)d_in[17];
    const float* bm1  = (const float*)d_in[18];
    float* out = (float*)d_out;

    // ws layout
    float* agg  = (float*)d_ws;                          // N*192
    float* hbuf = agg + (size_t)NN * 192;                // N*64
    int*   gcnt = (int*)(hbuf + (size_t)NN * 64);        // NBK
    int*   off  = gcnt + NBK;                            // NBK+1
    int*   cur  = off + (NBK + 2);                       // NBK
    int2*  brec = (int2*)(cur + NBK + 2);                // 3E records

    const int gemm_grid = (NN + 63) / 64;
    const int e_grid = (3 * EE + 255) / 256;

    // ---- bucket sort of edges (shared by both UFG blocks)
    hipMemsetAsync(gcnt, 0, NBK * sizeof(int), stream);
    hist_bucket<<<256, 256, 0, stream>>>(ei1, ei2, ei3, gcnt);
    scan_buckets<<<1, 1024, 0, stream>>>(gcnt, off, cur);
    bucket_scatter<<<e_grid, 256, 0, stream>>>(ei1, ea1, ei2, ea2, ei3, ea3,
                                               cur, brec);

    // ---- block 1
    gemm_n64<FF, false><<<gemm_grid, 256, 0, stream>>>(x, W1, b1, hbuf, NN);
    ufg_bucket<<<NBK, 256, 0, stream>>>(hbuf, off, brec,
                                        f1_1, f1_2, f1_3, agg);
    gemm_n64<192, true><<<gemm_grid, 256, 0, stream>>>(agg, Wm2, bm2, hbuf, NN);

    // ---- block 2
    ufg_bucket<<<NBK, 256, 0, stream>>>(hbuf, off, brec,
                                        f2_1, f2_2, f2_3, agg);
    gemm_softmax<<<2048, 256, 0, stream>>>(agg, Wm1, bm1, out);
}

// Round 5
// 1152.042 us; speedup vs baseline: 2.6551x; 2.6551x over previous
//
#include <hip/hip_runtime.h>
#include <hip/hip_bf16.h>

#define NN 100000
#define FF 500
#define HH 64
#define CC 40
#define EE 1000000
#define NB 782            // buckets per scale: ceil(100000/128)
#define NBK 2346          // 3*NB

// ---------------------------------------------------------------------------
// GEMM: C[N][64] = (opt relu)(A[N][K]) @ B[K][64] + bias[64]
// OBF16: write output as bf16 (for h consumed by the gather), else f32.
// ---------------------------------------------------------------------------
template <int K, bool RELU, bool OBF16>
__global__ __launch_bounds__(256) void gemm_n64(
    const float* __restrict__ A,
    const float* __restrict__ B,
    const float* __restrict__ bias,
    void* __restrict__ Cv,
    int nrows)
{
    __shared__ float As[32][68];
    __shared__ float Bs[32][64];

    const int tid = threadIdx.x;
    const int tx = tid & 15;
    const int ty = tid >> 4;
    const int row0 = blockIdx.x * 64;

    float acc[4][4] = {{0.f, 0.f, 0.f, 0.f}, {0.f, 0.f, 0.f, 0.f},
                       {0.f, 0.f, 0.f, 0.f}, {0.f, 0.f, 0.f, 0.f}};

    const int r = tid >> 2;
    const int koff = (tid & 3) * 8;
    const bool rowok = (row0 + r) < nrows;

    for (int k0 = 0; k0 < K; k0 += 32) {
        float av[8];
        const float* ap = A + (size_t)(row0 + r) * K + (k0 + koff);
        if (rowok && ((K % 32 == 0) || (k0 + 32 <= K))) {
            float4 v0 = *(const float4*)(ap);
            float4 v1 = *(const float4*)(ap + 4);
            av[0] = v0.x; av[1] = v0.y; av[2] = v0.z; av[3] = v0.w;
            av[4] = v1.x; av[5] = v1.y; av[6] = v1.z; av[7] = v1.w;
        } else {
            #pragma unroll
            for (int j = 0; j < 8; ++j) {
                int kk = k0 + koff + j;
                av[j] = (rowok && kk < K) ? ap[j] : 0.f;
            }
        }
        if (RELU) {
            #pragma unroll
            for (int j = 0; j < 8; ++j) av[j] = fmaxf(av[j], 0.f);
        }
        #pragma unroll
        for (int j = 0; j < 8; ++j) As[koff + j][r] = av[j];

        {
            int flat = tid * 8;
            int kk = flat >> 6;
            int c = flat & 63;
            float4 b0, b1v;
            if (k0 + kk < K) {
                b0 = *(const float4*)(B + (size_t)(k0 + kk) * 64 + c);
                b1v = *(const float4*)(B + (size_t)(k0 + kk) * 64 + c + 4);
            } else {
                b0 = make_float4(0.f, 0.f, 0.f, 0.f);
                b1v = b0;
            }
            *(float4*)&Bs[kk][c] = b0;
            *(float4*)&Bs[kk][c + 4] = b1v;
        }
        __syncthreads();

        #pragma unroll
        for (int k = 0; k < 32; ++k) {
            float4 a = *(const float4*)&As[k][ty * 4];
            float4 b = *(const float4*)&Bs[k][tx * 4];
            acc[0][0] = fmaf(a.x, b.x, acc[0][0]);
            acc[0][1] = fmaf(a.x, b.y, acc[0][1]);
            acc[0][2] = fmaf(a.x, b.z, acc[0][2]);
            acc[0][3] = fmaf(a.x, b.w, acc[0][3]);
            acc[1][0] = fmaf(a.y, b.x, acc[1][0]);
            acc[1][1] = fmaf(a.y, b.y, acc[1][1]);
            acc[1][2] = fmaf(a.y, b.z, acc[1][2]);
            acc[1][3] = fmaf(a.y, b.w, acc[1][3]);
            acc[2][0] = fmaf(a.z, b.x, acc[2][0]);
            acc[2][1] = fmaf(a.z, b.y, acc[2][1]);
            acc[2][2] = fmaf(a.z, b.z, acc[2][2]);
            acc[2][3] = fmaf(a.z, b.w, acc[2][3]);
            acc[3][0] = fmaf(a.w, b.x, acc[3][0]);
            acc[3][1] = fmaf(a.w, b.y, acc[3][1]);
            acc[3][2] = fmaf(a.w, b.z, acc[3][2]);
            acc[3][3] = fmaf(a.w, b.w, acc[3][3]);
        }
        __syncthreads();
    }

    float4 bv = *(const float4*)(bias + tx * 4);
    #pragma unroll
    for (int i = 0; i < 4; ++i) {
        int rr = row0 + ty * 4 + i;
        if (rr < nrows) {
            float o0 = acc[i][0] + bv.x;
            float o1 = acc[i][1] + bv.y;
            float o2 = acc[i][2] + bv.z;
            float o3 = acc[i][3] + bv.w;
            if (OBF16) {
                __hip_bfloat16* Cb = (__hip_bfloat16*)Cv;
                __hip_bfloat162 lo = __float22bfloat162_rn(make_float2(o0, o1));
                __hip_bfloat162 hi = __float22bfloat162_rn(make_float2(o2, o3));
                *(__hip_bfloat162*)(Cb + (size_t)rr * 64 + tx * 4) = lo;
                *(__hip_bfloat162*)(Cb + (size_t)rr * 64 + tx * 4 + 2) = hi;
            } else {
                float* C = (float*)Cv;
                *(float4*)(C + (size_t)rr * 64 + tx * 4) =
                    make_float4(o0, o1, o2, o3);
            }
        }
    }
}

// ---------------------------------------------------------------------------
// Bucket histogram: bucket = (scale, dst>>7). LDS-aggregated.
// ---------------------------------------------------------------------------
__global__ __launch_bounds__(256) void hist_bucket(
    const int* __restrict__ ei1, const int* __restrict__ ei2,
    const int* __restrict__ ei3, int* __restrict__ gcnt)
{
    __shared__ int lc[NBK];
    for (int j = threadIdx.x; j < NBK; j += 256) lc[j] = 0;
    __syncthreads();
    for (int i = blockIdx.x * 256 + threadIdx.x; i < 3 * EE;
         i += gridDim.x * 256) {
        int s = i / EE;
        int e = i - s * EE;
        const int* ei = (s == 0) ? ei1 : (s == 1) ? ei2 : ei3;
        int dst = ei[EE + e];
        atomicAdd(&lc[s * NB + (dst >> 7)], 1);
    }
    __syncthreads();
    for (int j = threadIdx.x; j < NBK; j += 256)
        if (lc[j]) atomicAdd(&gcnt[j], lc[j]);
}

// ---------------------------------------------------------------------------
// Single-block exclusive scan over NBK bucket counters.
// ---------------------------------------------------------------------------
__global__ __launch_bounds__(1024) void scan_buckets(
    const int* __restrict__ cnt, int* __restrict__ off, int* __restrict__ cur)
{
    __shared__ int sh[1024];
    __shared__ int carry;
    if (threadIdx.x == 0) carry = 0;
    __syncthreads();
    for (int base = 0; base < NBK; base += 1024) {
        int i = base + threadIdx.x;
        int v = (i < NBK) ? cnt[i] : 0;
        sh[threadIdx.x] = v;
        __syncthreads();
        #pragma unroll
        for (int o = 1; o < 1024; o <<= 1) {
            int add = (threadIdx.x >= o) ? sh[threadIdx.x - o] : 0;
            __syncthreads();
            sh[threadIdx.x] += add;
            __syncthreads();
        }
        int excl = sh[threadIdx.x] - v + carry;
        if (i < NBK) { off[i] = excl; cur[i] = excl; }
        __syncthreads();
        if (threadIdx.x == 1023) carry += sh[1023];
        __syncthreads();
    }
    if (threadIdx.x == 0) off[NBK] = 3 * EE;
}

// ---------------------------------------------------------------------------
// Bucket scatter: record = (src | dst_local<<17, weight). 2346-cursor write
// frontier -> L2-resident -> full-line merges (proven cheap in round 4).
// ---------------------------------------------------------------------------
__global__ __launch_bounds__(256) void bucket_scatter(
    const int* __restrict__ ei1, const float* __restrict__ ea1,
    const int* __restrict__ ei2, const float* __restrict__ ea2,
    const int* __restrict__ ei3, const float* __restrict__ ea3,
    int* __restrict__ cur, int2* __restrict__ brec)
{
    int i = blockIdx.x * 256 + threadIdx.x;
    if (i >= 3 * EE) return;
    int s = i / EE;
    int e = i - s * EE;
    const int* ei = (s == 0) ? ei1 : (s == 1) ? ei2 : ei3;
    const float* ea = (s == 0) ? ea1 : (s == 1) ? ea2 : ea3;
    int src = ei[e];
    int dst = ei[EE + e];
    float w = ea[e];
    int pos = atomicAdd(&cur[s * NB + (dst >> 7)], 1);
    brec[pos] = make_int2(src | ((dst & 127) << 17), __float_as_int(w));
}

// ---------------------------------------------------------------------------
// Bucket refine: one block per bucket. Two passes over the bucket's records:
// (1) LDS histogram of the 128 local dsts, scan, write per-node offsets;
// (2) place records to their final dst-sorted slots (writes land in the
// bucket's ~10 KB window -> L2 merges). Emits pure (src, weight) pairs.
// ---------------------------------------------------------------------------
__global__ __launch_bounds__(256) void bucket_refine(
    const int2* __restrict__ brec,
    const int* __restrict__ off_b,      // [NBK+1]
    int* __restrict__ node_off,         // [3N+1]
    int2* __restrict__ pairs)
{
    __shared__ int hist[128];
    __shared__ int curls[128];
    const int t = threadIdx.x;
    const int bk = blockIdx.x;
    const int s = bk / NB;
    const int b = bk - s * NB;
    const int n0 = b << 7;
    const int beg = off_b[bk];
    const int end = off_b[bk + 1];

    if (bk == 0 && t == 0) node_off[3 * NN] = 3 * EE;
    if (t < 128) hist[t] = 0;
    __syncthreads();

    for (int p = beg + t; p < end; p += 256)
        atomicAdd(&hist[(brec[p].x >> 17) & 127], 1);
    __syncthreads();

    int cnt = (t < 128) ? hist[t] : 0;
    #pragma unroll
    for (int o = 1; o < 128; o <<= 1) {
        int add = (t < 128 && t >= o) ? hist[t - o] : 0;
        __syncthreads();
        if (t < 128) hist[t] += add;
        __syncthreads();
    }
    if (t < 128) {
        int excl = beg + hist[t] - cnt;
        curls[t] = excl;
        if (n0 + t < NN) node_off[s * NN + n0 + t] = excl;
    }
    __syncthreads();

    for (int p = beg + t; p < end; p += 256) {
        int2 r = brec[p];
        int pos = atomicAdd(&curls[(r.x >> 17) & 127], 1);
        pairs[pos] = make_int2(r.x & 0x1FFFF, r.y);
    }
}

// ---------------------------------------------------------------------------
// Segmented gather (round-3 structure, bf16 h): one wave per (node, scale);
// lane = column; 8-deep ILP.
// ---------------------------------------------------------------------------
__global__ __launch_bounds__(256) void ufg_gather(
    const __hip_bfloat16* __restrict__ h,   // [N][64] bf16
    const int* __restrict__ off,            // [3N+1]
    const int2* __restrict__ pairs,         // [3E]
    const float* __restrict__ f1, const float* __restrict__ f2,
    const float* __restrict__ f3,
    float* __restrict__ agg)                // [N][192]
{
    const int lane = threadIdx.x & 63;
    const int wid = blockIdx.x * 4 + (threadIdx.x >> 6);
    if (wid >= 3 * NN) return;
    const int s = wid / NN;
    const int n = wid - s * NN;

    const float* fp = (s == 0) ? f1 : (s == 1) ? f2 : f3;
    const float fv = fp[lane];
    const __hip_bfloat16* hl = h + lane;

    const int beg = off[wid];
    const int end = off[wid + 1];

    float acc0 = 0.f, acc1 = 0.f;
    int p = beg;

    for (; p + 8 <= end; p += 8) {
        int2 q0 = pairs[p + 0];
        int2 q1 = pairs[p + 1];
        int2 q2 = pairs[p + 2];
        int2 q3 = pairs[p + 3];
        int2 q4 = pairs[p + 4];
        int2 q5 = pairs[p + 5];
        int2 q6 = pairs[p + 6];
        int2 q7 = pairs[p + 7];
        float v0 = __bfloat162float(hl[(size_t)q0.x * 64]);
        float v1 = __bfloat162float(hl[(size_t)q1.x * 64]);
        float v2 = __bfloat162float(hl[(size_t)q2.x * 64]);
        float v3 = __bfloat162float(hl[(size_t)q3.x * 64]);
        float v4 = __bfloat162float(hl[(size_t)q4.x * 64]);
        float v5 = __bfloat162float(hl[(size_t)q5.x * 64]);
        float v6 = __bfloat162float(hl[(size_t)q6.x * 64]);
        float v7 = __bfloat162float(hl[(size_t)q7.x * 64]);
        acc0 = fmaf(__int_as_float(q0.y), v0, acc0);
        acc1 = fmaf(__int_as_float(q1.y), v1, acc1);
        acc0 = fmaf(__int_as_float(q2.y), v2, acc0);
        acc1 = fmaf(__int_as_float(q3.y), v3, acc1);
        acc0 = fmaf(__int_as_float(q4.y), v4, acc0);
        acc1 = fmaf(__int_as_float(q5.y), v5, acc1);
        acc0 = fmaf(__int_as_float(q6.y), v6, acc0);
        acc1 = fmaf(__int_as_float(q7.y), v7, acc1);
    }
    if (p + 4 <= end) {
        int2 q0 = pairs[p + 0];
        int2 q1 = pairs[p + 1];
        int2 q2 = pairs[p + 2];
        int2 q3 = pairs[p + 3];
        float v0 = __bfloat162float(hl[(size_t)q0.x * 64]);
        float v1 = __bfloat162float(hl[(size_t)q1.x * 64]);
        float v2 = __bfloat162float(hl[(size_t)q2.x * 64]);
        float v3 = __bfloat162float(hl[(size_t)q3.x * 64]);
        acc0 = fmaf(__int_as_float(q0.y), v0, acc0);
        acc1 = fmaf(__int_as_float(q1.y), v1, acc1);
        acc0 = fmaf(__int_as_float(q2.y), v2, acc0);
        acc1 = fmaf(__int_as_float(q3.y), v3, acc1);
        p += 4;
    }
    if (p + 2 <= end) {
        int2 q0 = pairs[p + 0];
        int2 q1 = pairs[p + 1];
        float v0 = __bfloat162float(hl[(size_t)q0.x * 64]);
        float v1 = __bfloat162float(hl[(size_t)q1.x * 64]);
        acc0 = fmaf(__int_as_float(q0.y), v0, acc0);
        acc1 = fmaf(__int_as_float(q1.y), v1, acc1);
        p += 2;
    }
    if (p < end) {
        int2 q = pairs[p];
        acc0 = fmaf(__int_as_float(q.y),
                    __bfloat162float(hl[(size_t)q.x * 64]), acc0);
    }

    agg[(size_t)n * 192 + s * 64 + lane] = (acc0 + acc1) * fv;
}

// ---------------------------------------------------------------------------
// GEMM3 + log_softmax
// ---------------------------------------------------------------------------
__global__ __launch_bounds__(256) void gemm_softmax(
    const float* __restrict__ A, const float* __restrict__ W,
    const float* __restrict__ bias, float* __restrict__ out)
{
    __shared__ float Ws[192 * 40];
    for (int i = threadIdx.x; i < 192 * 40; i += 256) Ws[i] = W[i];
    __syncthreads();

    const int lane = threadIdx.x & 63;
    const int wv = threadIdx.x >> 6;
    const bool act = lane < 40;
    const int cl = act ? lane : 39;

    for (int row = blockIdx.x * 4 + wv; row < NN; row += gridDim.x * 4) {
        const float* a = A + (size_t)row * 192;
        float acc = bias[cl];
        #pragma unroll 8
        for (int k0 = 0; k0 < 192; k0 += 4) {
            float4 av = *(const float4*)(a + k0);
            av.x = fmaxf(av.x, 0.f);
            av.y = fmaxf(av.y, 0.f);
            av.z = fmaxf(av.z, 0.f);
            av.w = fmaxf(av.w, 0.f);
            acc = fmaf(av.x, Ws[(k0 + 0) * 40 + cl], acc);
            acc = fmaf(av.y, Ws[(k0 + 1) * 40 + cl], acc);
            acc = fmaf(av.z, Ws[(k0 + 2) * 40 + cl], acc);
            acc = fmaf(av.w, Ws[(k0 + 3) * 40 + cl], acc);
        }
        float v = act ? acc : -1e30f;
        #pragma unroll
        for (int off = 32; off > 0; off >>= 1)
            v = fmaxf(v, __shfl_xor(v, off, 64));
        float ex = act ? __expf(acc - v) : 0.f;
        float s = ex;
        #pragma unroll
        for (int off = 32; off > 0; off >>= 1)
            s += __shfl_xor(s, off, 64);
        if (act) out[(size_t)row * 40 + lane] = acc - v - __logf(s);
    }
}

// ---------------------------------------------------------------------------
extern "C" void kernel_launch(void* const* d_in, const int* in_sizes, int n_in,
                              void* d_out, int out_size, void* d_ws, size_t ws_size,
                              hipStream_t stream)
{
    const float* x    = (const float*)d_in[0];
    const int*   ei1  = (const int*)d_in[1];
    const float* ea1  = (const float*)d_in[2];
    const int*   ei2  = (const int*)d_in[3];
    const float* ea2  = (const float*)d_in[4];
    const int*   ei3  = (const int*)d_in[5];
    const float* ea3  = (const float*)d_in[6];
    const float* W1   = (const float*)d_in[7];
    const float* b1   = (const float*)d_in[8];
    const float* f1_1 = (const float*)d_in[9];
    const float* f2_1 = (const float*)d_in[10];
    const float* f1_2 = (const float*)d_in[11];
    const float* f2_2 = (const float*)d_in[12];
    const float* f1_3 = (const float*)d_in[13];
    const float* f2_3 = (const float*)d_in[14];
    const float* Wm2  = (const float*)d_in[15];
    const float* bm2  = (const float*)d_in[16];
    const float* Wm1  = (const float*)d_in[17];
    const float* bm1  = (const float*)d_in[18];
    float* out = (float*)d_out;

    // ws layout. brec aliases agg: brec is dead before agg's first write
    // (ufg_gather #1 runs after bucket_refine has consumed brec).
    float* agg  = (float*)d_ws;                              // N*192 f32
    int2*  brec = (int2*)d_ws;                               // 3E int2 (alias)
    char*  base = (char*)d_ws + (size_t)NN * 192 * 4;
    __hip_bfloat16* hbuf = (__hip_bfloat16*)base;            // N*64 bf16
    int*   gcnt = (int*)(base + (size_t)NN * 64 * 2);        // NBK
    int*   off_b = gcnt + NBK;                               // NBK+1 (pad 2)
    int*   cur  = off_b + NBK + 2;                           // NBK
    int*   node_off = cur + NBK;                             // 3N+1 (pad 2)
    int2*  pairs = (int2*)(node_off + 3 * NN + 2);           // 3E int2

    const int gemm_grid = (NN + 63) / 64;
    const int e_grid = (3 * EE + 255) / 256;

    // ---- dst-sort edges (coarse bucket pass + per-bucket refine) ----
    hipMemsetAsync(gcnt, 0, NBK * sizeof(int), stream);
    hist_bucket<<<256, 256, 0, stream>>>(ei1, ei2, ei3, gcnt);
    scan_buckets<<<1, 1024, 0, stream>>>(gcnt, off_b, cur);
    bucket_scatter<<<e_grid, 256, 0, stream>>>(ei1, ea1, ei2, ea2, ei3, ea3,
                                               cur, brec);
    bucket_refine<<<NBK, 256, 0, stream>>>(brec, off_b, node_off, pairs);

    // ---- block 1 ----
    gemm_n64<FF, false, true><<<gemm_grid, 256, 0, stream>>>(x, W1, b1,
                                                             hbuf, NN);
    ufg_gather<<<(3 * NN + 3) / 4, 256, 0, stream>>>(hbuf, node_off, pairs,
                                                     f1_1, f1_2, f1_3, agg);
    gemm_n64<192, true, true><<<gemm_grid, 256, 0, stream>>>(agg, Wm2, bm2,
                                                             hbuf, NN);

    // ---- block 2 ----
    ufg_gather<<<(3 * NN + 3) / 4, 256, 0, stream>>>(hbuf, node_off, pairs,
                                                     f2_1, f2_2, f2_3, agg);
    gemm_softmax<<<2048, 256, 0, stream>>>(agg, Wm1, bm1, out);
}

// Round 6
// 636.693 us; speedup vs baseline: 4.8042x; 1.8094x over previous
//
#include <hip/hip_runtime.h>
#include <hip/hip_bf16.h>

#define NN 100000
#define FF 500
#define HH 64
#define CC 40
#define EE 1000000
#define NB 782            // buckets per scale: ceil(100000/128)
#define NBK 2346          // 3*NB
#define NBLK_P 128        // partition blocks
#define M2 (NBK * NBLK_P) // 300288 counters

// ---------------------------------------------------------------------------
// GEMM: C[N][64] = (opt relu)(A[N][K]) @ B[K][64] + bias[64]
// OBF16: write output as bf16 (consumed by the gather).
// ---------------------------------------------------------------------------
template <int K, bool RELU, bool OBF16>
__global__ __launch_bounds__(256) void gemm_n64(
    const float* __restrict__ A,
    const float* __restrict__ B,
    const float* __restrict__ bias,
    void* __restrict__ Cv,
    int nrows)
{
    __shared__ float As[32][68];
    __shared__ float Bs[32][64];

    const int tid = threadIdx.x;
    const int tx = tid & 15;
    const int ty = tid >> 4;
    const int row0 = blockIdx.x * 64;

    float acc[4][4] = {{0.f, 0.f, 0.f, 0.f}, {0.f, 0.f, 0.f, 0.f},
                       {0.f, 0.f, 0.f, 0.f}, {0.f, 0.f, 0.f, 0.f}};

    const int r = tid >> 2;
    const int koff = (tid & 3) * 8;
    const bool rowok = (row0 + r) < nrows;

    for (int k0 = 0; k0 < K; k0 += 32) {
        float av[8];
        const float* ap = A + (size_t)(row0 + r) * K + (k0 + koff);
        if (rowok && ((K % 32 == 0) || (k0 + 32 <= K))) {
            float4 v0 = *(const float4*)(ap);
            float4 v1 = *(const float4*)(ap + 4);
            av[0] = v0.x; av[1] = v0.y; av[2] = v0.z; av[3] = v0.w;
            av[4] = v1.x; av[5] = v1.y; av[6] = v1.z; av[7] = v1.w;
        } else {
            #pragma unroll
            for (int j = 0; j < 8; ++j) {
                int kk = k0 + koff + j;
                av[j] = (rowok && kk < K) ? ap[j] : 0.f;
            }
        }
        if (RELU) {
            #pragma unroll
            for (int j = 0; j < 8; ++j) av[j] = fmaxf(av[j], 0.f);
        }
        #pragma unroll
        for (int j = 0; j < 8; ++j) As[koff + j][r] = av[j];

        {
            int flat = tid * 8;
            int kk = flat >> 6;
            int c = flat & 63;
            float4 b0, b1v;
            if (k0 + kk < K) {
                b0 = *(const float4*)(B + (size_t)(k0 + kk) * 64 + c);
                b1v = *(const float4*)(B + (size_t)(k0 + kk) * 64 + c + 4);
            } else {
                b0 = make_float4(0.f, 0.f, 0.f, 0.f);
                b1v = b0;
            }
            *(float4*)&Bs[kk][c] = b0;
            *(float4*)&Bs[kk][c + 4] = b1v;
        }
        __syncthreads();

        #pragma unroll
        for (int k = 0; k < 32; ++k) {
            float4 a = *(const float4*)&As[k][ty * 4];
            float4 b = *(const float4*)&Bs[k][tx * 4];
            acc[0][0] = fmaf(a.x, b.x, acc[0][0]);
            acc[0][1] = fmaf(a.x, b.y, acc[0][1]);
            acc[0][2] = fmaf(a.x, b.z, acc[0][2]);
            acc[0][3] = fmaf(a.x, b.w, acc[0][3]);
            acc[1][0] = fmaf(a.y, b.x, acc[1][0]);
            acc[1][1] = fmaf(a.y, b.y, acc[1][1]);
            acc[1][2] = fmaf(a.y, b.z, acc[1][2]);
            acc[1][3] = fmaf(a.y, b.w, acc[1][3]);
            acc[2][0] = fmaf(a.z, b.x, acc[2][0]);
            acc[2][1] = fmaf(a.z, b.y, acc[2][1]);
            acc[2][2] = fmaf(a.z, b.z, acc[2][2]);
            acc[2][3] = fmaf(a.z, b.w, acc[2][3]);
            acc[3][0] = fmaf(a.w, b.x, acc[3][0]);
            acc[3][1] = fmaf(a.w, b.y, acc[3][1]);
            acc[3][2] = fmaf(a.w, b.z, acc[3][2]);
            acc[3][3] = fmaf(a.w, b.w, acc[3][3]);
        }
        __syncthreads();
    }

    float4 bv = *(const float4*)(bias + tx * 4);
    #pragma unroll
    for (int i = 0; i < 4; ++i) {
        int rr = row0 + ty * 4 + i;
        if (rr < nrows) {
            float o0 = acc[i][0] + bv.x;
            float o1 = acc[i][1] + bv.y;
            float o2 = acc[i][2] + bv.z;
            float o3 = acc[i][3] + bv.w;
            if (OBF16) {
                __hip_bfloat16* Cb = (__hip_bfloat16*)Cv;
                __hip_bfloat162 lo = __float22bfloat162_rn(make_float2(o0, o1));
                __hip_bfloat162 hi = __float22bfloat162_rn(make_float2(o2, o3));
                *(__hip_bfloat162*)(Cb + (size_t)rr * 64 + tx * 4) = lo;
                *(__hip_bfloat162*)(Cb + (size_t)rr * 64 + tx * 4 + 2) = hi;
            } else {
                float* C = (float*)Cv;
                *(float4*)(C + (size_t)rr * 64 + tx * 4) =
                    make_float4(o0, o1, o2, o3);
            }
        }
    }
}

// ---------------------------------------------------------------------------
// Radix partition pass 1: per-block private bucket histogram (LDS only),
// written out bucket-major: cnt[bucket * NBLK_P + blk]. No global atomics.
// ---------------------------------------------------------------------------
__global__ __launch_bounds__(1024) void part_count(
    const int* __restrict__ ei1, const int* __restrict__ ei2,
    const int* __restrict__ ei3, int* __restrict__ cnt)
{
    __shared__ int lc[NBK];
    const int t = threadIdx.x;
    for (int j = t; j < NBK; j += 1024) lc[j] = 0;
    __syncthreads();

    const int chunk = (3 * EE + NBLK_P - 1) / NBLK_P;
    const int b0 = blockIdx.x * chunk;
    int b1 = b0 + chunk;
    if (b1 > 3 * EE) b1 = 3 * EE;

    for (int i = b0 + t; i < b1; i += 1024) {
        int s = i / EE;
        int e = i - s * EE;
        const int* ei = (s == 0) ? ei1 : (s == 1) ? ei2 : ei3;
        atomicAdd(&lc[s * NB + (ei[EE + e] >> 7)], 1);
    }
    __syncthreads();
    for (int j = t; j < NBK; j += 1024)
        cnt[j * NBLK_P + blockIdx.x] = lc[j];
}

// ---------------------------------------------------------------------------
// Exclusive scan over M2 counters: per-block scan + partials + add-bases.
// ---------------------------------------------------------------------------
__global__ __launch_bounds__(1024) void scan_a(
    const int* __restrict__ cnt, int* __restrict__ off,
    int* __restrict__ partials, int M)
{
    __shared__ int sh[1024];
    int t = threadIdx.x;
    int i = blockIdx.x * 1024 + t;
    int v = (i < M) ? cnt[i] : 0;
    sh[t] = v;
    __syncthreads();
    #pragma unroll
    for (int o = 1; o < 1024; o <<= 1) {
        int add = (t >= o) ? sh[t - o] : 0;
        __syncthreads();
        sh[t] += add;
        __syncthreads();
    }
    if (i < M) off[i] = sh[t] - v;
    if (t == 1023) partials[blockIdx.x] = sh[1023];
}

__global__ __launch_bounds__(512) void scan_b(int* __restrict__ partials, int P)
{
    __shared__ int sh[512];
    int t = threadIdx.x;
    int v = (t < P) ? partials[t] : 0;
    sh[t] = v;
    __syncthreads();
    #pragma unroll
    for (int o = 1; o < 512; o <<= 1) {
        int add = (t >= o) ? sh[t - o] : 0;
        __syncthreads();
        sh[t] += add;
        __syncthreads();
    }
    if (t < P) partials[t] = sh[t] - v;
}

// add block bases; extract per-bucket segment starts into off_b
__global__ __launch_bounds__(256) void scan_c(
    int* __restrict__ off, int* __restrict__ off_b,
    const int* __restrict__ partials, int M)
{
    int i = blockIdx.x * 256 + threadIdx.x;
    if (i < M) {
        int v = off[i] + partials[i >> 10];
        off[i] = v;
        if ((i & (NBLK_P - 1)) == 0) off_b[i / NBLK_P] = v;
    }
    if (i == 0) off_b[NBK] = 3 * EE;
}

// ---------------------------------------------------------------------------
// Radix partition pass 2: re-walk the same edge range; place records via LDS
// cursors (base from scanned cnt). record = (src | dst_local<<17, weight).
// Per-(block,bucket) output slices are contiguous -> write merging, and no
// global atomics at all.
// ---------------------------------------------------------------------------
__global__ __launch_bounds__(1024) void part_scatter(
    const int* __restrict__ ei1, const float* __restrict__ ea1,
    const int* __restrict__ ei2, const float* __restrict__ ea2,
    const int* __restrict__ ei3, const float* __restrict__ ea3,
    const int* __restrict__ offp, int2* __restrict__ brec)
{
    __shared__ int lcur[NBK];
    const int t = threadIdx.x;
    for (int j = t; j < NBK; j += 1024)
        lcur[j] = offp[j * NBLK_P + blockIdx.x];
    __syncthreads();

    const int chunk = (3 * EE + NBLK_P - 1) / NBLK_P;
    const int b0 = blockIdx.x * chunk;
    int b1 = b0 + chunk;
    if (b1 > 3 * EE) b1 = 3 * EE;

    for (int i = b0 + t; i < b1; i += 1024) {
        int s = i / EE;
        int e = i - s * EE;
        const int* ei = (s == 0) ? ei1 : (s == 1) ? ei2 : ei3;
        const float* ea = (s == 0) ? ea1 : (s == 1) ? ea2 : ea3;
        int src = ei[e];
        int dst = ei[EE + e];
        float w = ea[e];
        int pos = atomicAdd(&lcur[s * NB + (dst >> 7)], 1);
        brec[pos] = make_int2(src | ((dst & 127) << 17), __float_as_int(w));
    }
}

// ---------------------------------------------------------------------------
// Bucket refine: one block per bucket; LDS counting sort of 128 local dsts.
// Emits dst-sorted (src, weight) pairs + per-node offsets.
// ---------------------------------------------------------------------------
__global__ __launch_bounds__(256) void bucket_refine(
    const int2* __restrict__ brec,
    const int* __restrict__ off_b,      // [NBK+1]
    int* __restrict__ node_off,         // [3N+1]
    int2* __restrict__ pairs)
{
    __shared__ int hist[128];
    __shared__ int curls[128];
    const int t = threadIdx.x;
    const int bk = blockIdx.x;
    const int s = bk / NB;
    const int b = bk - s * NB;
    const int n0 = b << 7;
    const int beg = off_b[bk];
    const int end = off_b[bk + 1];

    if (bk == 0 && t == 0) node_off[3 * NN] = 3 * EE;
    if (t < 128) hist[t] = 0;
    __syncthreads();

    for (int p = beg + t; p < end; p += 256)
        atomicAdd(&hist[(brec[p].x >> 17) & 127], 1);
    __syncthreads();

    int cnt = (t < 128) ? hist[t] : 0;
    #pragma unroll
    for (int o = 1; o < 128; o <<= 1) {
        int add = (t < 128 && t >= o) ? hist[t - o] : 0;
        __syncthreads();
        if (t < 128) hist[t] += add;
        __syncthreads();
    }
    if (t < 128) {
        int excl = beg + hist[t] - cnt;
        curls[t] = excl;
        if (n0 + t < NN) node_off[s * NN + n0 + t] = excl;
    }
    __syncthreads();

    for (int p = beg + t; p < end; p += 256) {
        int2 r = brec[p];
        int pos = atomicAdd(&curls[(r.x >> 17) & 127], 1);
        pairs[pos] = make_int2(r.x & 0x1FFFF, r.y);
    }
}

// ---------------------------------------------------------------------------
// Segmented gather (bf16 h): one wave per (node, scale); lane = column;
// 8-deep ILP.
// ---------------------------------------------------------------------------
__global__ __launch_bounds__(256) void ufg_gather(
    const __hip_bfloat16* __restrict__ h,   // [N][64] bf16
    const int* __restrict__ off,            // [3N+1]
    const int2* __restrict__ pairs,         // [3E]
    const float* __restrict__ f1, const float* __restrict__ f2,
    const float* __restrict__ f3,
    float* __restrict__ agg)                // [N][192]
{
    const int lane = threadIdx.x & 63;
    const int wid = blockIdx.x * 4 + (threadIdx.x >> 6);
    if (wid >= 3 * NN) return;
    const int s = wid / NN;
    const int n = wid - s * NN;

    const float* fp = (s == 0) ? f1 : (s == 1) ? f2 : f3;
    const float fv = fp[lane];
    const __hip_bfloat16* hl = h + lane;

    const int beg = off[wid];
    const int end = off[wid + 1];

    float acc0 = 0.f, acc1 = 0.f;
    int p = beg;

    for (; p + 8 <= end; p += 8) {
        int2 q0 = pairs[p + 0];
        int2 q1 = pairs[p + 1];
        int2 q2 = pairs[p + 2];
        int2 q3 = pairs[p + 3];
        int2 q4 = pairs[p + 4];
        int2 q5 = pairs[p + 5];
        int2 q6 = pairs[p + 6];
        int2 q7 = pairs[p + 7];
        float v0 = __bfloat162float(hl[(size_t)q0.x * 64]);
        float v1 = __bfloat162float(hl[(size_t)q1.x * 64]);
        float v2 = __bfloat162float(hl[(size_t)q2.x * 64]);
        float v3 = __bfloat162float(hl[(size_t)q3.x * 64]);
        float v4 = __bfloat162float(hl[(size_t)q4.x * 64]);
        float v5 = __bfloat162float(hl[(size_t)q5.x * 64]);
        float v6 = __bfloat162float(hl[(size_t)q6.x * 64]);
        float v7 = __bfloat162float(hl[(size_t)q7.x * 64]);
        acc0 = fmaf(__int_as_float(q0.y), v0, acc0);
        acc1 = fmaf(__int_as_float(q1.y), v1, acc1);
        acc0 = fmaf(__int_as_float(q2.y), v2, acc0);
        acc1 = fmaf(__int_as_float(q3.y), v3, acc1);
        acc0 = fmaf(__int_as_float(q4.y), v4, acc0);
        acc1 = fmaf(__int_as_float(q5.y), v5, acc1);
        acc0 = fmaf(__int_as_float(q6.y), v6, acc0);
        acc1 = fmaf(__int_as_float(q7.y), v7, acc1);
    }
    if (p + 4 <= end) {
        int2 q0 = pairs[p + 0];
        int2 q1 = pairs[p + 1];
        int2 q2 = pairs[p + 2];
        int2 q3 = pairs[p + 3];
        float v0 = __bfloat162float(hl[(size_t)q0.x * 64]);
        float v1 = __bfloat162float(hl[(size_t)q1.x * 64]);
        float v2 = __bfloat162float(hl[(size_t)q2.x * 64]);
        float v3 = __bfloat162float(hl[(size_t)q3.x * 64]);
        acc0 = fmaf(__int_as_float(q0.y), v0, acc0);
        acc1 = fmaf(__int_as_float(q1.y), v1, acc1);
        acc0 = fmaf(__int_as_float(q2.y), v2, acc0);
        acc1 = fmaf(__int_as_float(q3.y), v3, acc1);
        p += 4;
    }
    if (p + 2 <= end) {
        int2 q0 = pairs[p + 0];
        int2 q1 = pairs[p + 1];
        float v0 = __bfloat162float(hl[(size_t)q0.x * 64]);
        float v1 = __bfloat162float(hl[(size_t)q1.x * 64]);
        acc0 = fmaf(__int_as_float(q0.y), v0, acc0);
        acc1 = fmaf(__int_as_float(q1.y), v1, acc1);
        p += 2;
    }
    if (p < end) {
        int2 q = pairs[p];
        acc0 = fmaf(__int_as_float(q.y),
                    __bfloat162float(hl[(size_t)q.x * 64]), acc0);
    }

    agg[(size_t)n * 192 + s * 64 + lane] = (acc0 + acc1) * fv;
}

// ---------------------------------------------------------------------------
// GEMM3 + log_softmax
// ---------------------------------------------------------------------------
__global__ __launch_bounds__(256) void gemm_softmax(
    const float* __restrict__ A, const float* __restrict__ W,
    const float* __restrict__ bias, float* __restrict__ out)
{
    __shared__ float Ws[192 * 40];
    for (int i = threadIdx.x; i < 192 * 40; i += 256) Ws[i] = W[i];
    __syncthreads();

    const int lane = threadIdx.x & 63;
    const int wv = threadIdx.x >> 6;
    const bool act = lane < 40;
    const int cl = act ? lane : 39;

    for (int row = blockIdx.x * 4 + wv; row < NN; row += gridDim.x * 4) {
        const float* a = A + (size_t)row * 192;
        float acc = bias[cl];
        #pragma unroll 8
        for (int k0 = 0; k0 < 192; k0 += 4) {
            float4 av = *(const float4*)(a + k0);
            av.x = fmaxf(av.x, 0.f);
            av.y = fmaxf(av.y, 0.f);
            av.z = fmaxf(av.z, 0.f);
            av.w = fmaxf(av.w, 0.f);
            acc = fmaf(av.x, Ws[(k0 + 0) * 40 + cl], acc);
            acc = fmaf(av.y, Ws[(k0 + 1) * 40 + cl], acc);
            acc = fmaf(av.z, Ws[(k0 + 2) * 40 + cl], acc);
            acc = fmaf(av.w, Ws[(k0 + 3) * 40 + cl], acc);
        }
        float v = act ? acc : -1e30f;
        #pragma unroll
        for (int off = 32; off > 0; off >>= 1)
            v = fmaxf(v, __shfl_xor(v, off, 64));
        float ex = act ? __expf(acc - v) : 0.f;
        float s = ex;
        #pragma unroll
        for (int off = 32; off > 0; off >>= 1)
            s += __shfl_xor(s, off, 64);
        if (act) out[(size_t)row * 40 + lane] = acc - v - __logf(s);
    }
}

// ---------------------------------------------------------------------------
extern "C" void kernel_launch(void* const* d_in, const int* in_sizes, int n_in,
                              void* d_out, int out_size, void* d_ws, size_t ws_size,
                              hipStream_t stream)
{
    const float* x    = (const float*)d_in[0];
    const int*   ei1  = (const int*)d_in[1];
    const float* ea1  = (const float*)d_in[2];
    const int*   ei2  = (const int*)d_in[3];
    const float* ea2  = (const float*)d_in[4];
    const int*   ei3  = (const int*)d_in[5];
    const float* ea3  = (const float*)d_in[6];
    const float* W1   = (const float*)d_in[7];
    const float* b1   = (const float*)d_in[8];
    const float* f1_1 = (const float*)d_in[9];
    const float* f2_1 = (const float*)d_in[10];
    const float* f1_2 = (const float*)d_in[11];
    const float* f2_2 = (const float*)d_in[12];
    const float* f1_3 = (const float*)d_in[13];
    const float* f2_3 = (const float*)d_in[14];
    const float* Wm2  = (const float*)d_in[15];
    const float* bm2  = (const float*)d_in[16];
    const float* Wm1  = (const float*)d_in[17];
    const float* bm1  = (const float*)d_in[18];
    float* out = (float*)d_out;

    // ws layout. brec aliases agg: brec is dead before agg's first write
    // (ufg_gather #1 runs after bucket_refine has consumed brec).
    float* agg  = (float*)d_ws;                              // N*192 f32
    int2*  brec = (int2*)d_ws;                               // 3E int2 (alias)
    char*  base = (char*)d_ws + (size_t)NN * 192 * 4;
    __hip_bfloat16* hbuf = (__hip_bfloat16*)base;            // N*64 bf16
    int*   cnt  = (int*)(base + (size_t)NN * 64 * 2);        // M2
    int*   offp = cnt + M2;                                  // M2
    int*   part = offp + M2;                                 // 512
    int*   off_b = part + 512;                               // NBK+1 (+pad)
    int*   node_off = off_b + NBK + 2;                       // 3N+1 (+pad)
    int2*  pairs = (int2*)(node_off + 3 * NN + 2);           // 3E int2

    const int gemm_grid = (NN + 63) / 64;
    const int P = (M2 + 1023) / 1024;    // 294

    // ---- dst-sort edges: atomic-free radix partition + per-bucket refine
    part_count<<<NBLK_P, 1024, 0, stream>>>(ei1, ei2, ei3, cnt);
    scan_a<<<P, 1024, 0, stream>>>(cnt, offp, part, M2);
    scan_b<<<1, 512, 0, stream>>>(part, P);
    scan_c<<<(M2 + 255) / 256, 256, 0, stream>>>(offp, off_b, part, M2);
    part_scatter<<<NBLK_P, 1024, 0, stream>>>(ei1, ea1, ei2, ea2, ei3, ea3,
                                              offp, brec);
    bucket_refine<<<NBK, 256, 0, stream>>>(brec, off_b, node_off, pairs);

    // ---- block 1 ----
    gemm_n64<FF, false, true><<<gemm_grid, 256, 0, stream>>>(x, W1, b1,
                                                             hbuf, NN);
    ufg_gather<<<(3 * NN + 3) / 4, 256, 0, stream>>>(hbuf, node_off, pairs,
                                                     f1_1, f1_2, f1_3, agg);
    gemm_n64<192, true, true><<<gemm_grid, 256, 0, stream>>>(agg, Wm2, bm2,
                                                             hbuf, NN);

    // ---- block 2 ----
    ufg_gather<<<(3 * NN + 3) / 4, 256, 0, stream>>>(hbuf, node_off, pairs,
                                                     f2_1, f2_2, f2_3, agg);
    gemm_softmax<<<2048, 256, 0, stream>>>(agg, Wm1, bm1, out);
}

// Round 7
// 532.999 us; speedup vs baseline: 5.7388x; 1.1945x over previous
//
#include <hip/hip_runtime.h>
#include <hip/hip_bf16.h>

#define NN 100000
#define FF 500
#define HH 64
#define CC 40
#define EE 1000000
#define NB 782            // buckets per scale: ceil(100000/128)
#define NBK 2346          // 3*NB
#define NBLK_P 128        // partition blocks
#define M2 (NBK * NBLK_P) // 300288 counters

// ---------------------------------------------------------------------------
// GEMM: C[N][64] = (opt relu)(A[N][K]) @ B[K][64] + bias[64]
// OBF16: write output as bf16 (consumed by the gather).
// ---------------------------------------------------------------------------
template <int K, bool RELU, bool OBF16>
__global__ __launch_bounds__(256) void gemm_n64(
    const float* __restrict__ A,
    const float* __restrict__ B,
    const float* __restrict__ bias,
    void* __restrict__ Cv,
    int nrows)
{
    __shared__ float As[32][68];
    __shared__ float Bs[32][64];

    const int tid = threadIdx.x;
    const int tx = tid & 15;
    const int ty = tid >> 4;
    const int row0 = blockIdx.x * 64;

    float acc[4][4] = {{0.f, 0.f, 0.f, 0.f}, {0.f, 0.f, 0.f, 0.f},
                       {0.f, 0.f, 0.f, 0.f}, {0.f, 0.f, 0.f, 0.f}};

    const int r = tid >> 2;
    const int koff = (tid & 3) * 8;
    const bool rowok = (row0 + r) < nrows;

    for (int k0 = 0; k0 < K; k0 += 32) {
        float av[8];
        const float* ap = A + (size_t)(row0 + r) * K + (k0 + koff);
        if (rowok && ((K % 32 == 0) || (k0 + 32 <= K))) {
            float4 v0 = *(const float4*)(ap);
            float4 v1 = *(const float4*)(ap + 4);
            av[0] = v0.x; av[1] = v0.y; av[2] = v0.z; av[3] = v0.w;
            av[4] = v1.x; av[5] = v1.y; av[6] = v1.z; av[7] = v1.w;
        } else {
            #pragma unroll
            for (int j = 0; j < 8; ++j) {
                int kk = k0 + koff + j;
                av[j] = (rowok && kk < K) ? ap[j] : 0.f;
            }
        }
        if (RELU) {
            #pragma unroll
            for (int j = 0; j < 8; ++j) av[j] = fmaxf(av[j], 0.f);
        }
        #pragma unroll
        for (int j = 0; j < 8; ++j) As[koff + j][r] = av[j];

        {
            int flat = tid * 8;
            int kk = flat >> 6;
            int c = flat & 63;
            float4 b0, b1v;
            if (k0 + kk < K) {
                b0 = *(const float4*)(B + (size_t)(k0 + kk) * 64 + c);
                b1v = *(const float4*)(B + (size_t)(k0 + kk) * 64 + c + 4);
            } else {
                b0 = make_float4(0.f, 0.f, 0.f, 0.f);
                b1v = b0;
            }
            *(float4*)&Bs[kk][c] = b0;
            *(float4*)&Bs[kk][c + 4] = b1v;
        }
        __syncthreads();

        #pragma unroll
        for (int k = 0; k < 32; ++k) {
            float4 a = *(const float4*)&As[k][ty * 4];
            float4 b = *(const float4*)&Bs[k][tx * 4];
            acc[0][0] = fmaf(a.x, b.x, acc[0][0]);
            acc[0][1] = fmaf(a.x, b.y, acc[0][1]);
            acc[0][2] = fmaf(a.x, b.z, acc[0][2]);
            acc[0][3] = fmaf(a.x, b.w, acc[0][3]);
            acc[1][0] = fmaf(a.y, b.x, acc[1][0]);
            acc[1][1] = fmaf(a.y, b.y, acc[1][1]);
            acc[1][2] = fmaf(a.y, b.z, acc[1][2]);
            acc[1][3] = fmaf(a.y, b.w, acc[1][3]);
            acc[2][0] = fmaf(a.z, b.x, acc[2][0]);
            acc[2][1] = fmaf(a.z, b.y, acc[2][1]);
            acc[2][2] = fmaf(a.z, b.z, acc[2][2]);
            acc[2][3] = fmaf(a.z, b.w, acc[2][3]);
            acc[3][0] = fmaf(a.w, b.x, acc[3][0]);
            acc[3][1] = fmaf(a.w, b.y, acc[3][1]);
            acc[3][2] = fmaf(a.w, b.z, acc[3][2]);
            acc[3][3] = fmaf(a.w, b.w, acc[3][3]);
        }
        __syncthreads();
    }

    float4 bv = *(const float4*)(bias + tx * 4);
    #pragma unroll
    for (int i = 0; i < 4; ++i) {
        int rr = row0 + ty * 4 + i;
        if (rr < nrows) {
            float o0 = acc[i][0] + bv.x;
            float o1 = acc[i][1] + bv.y;
            float o2 = acc[i][2] + bv.z;
            float o3 = acc[i][3] + bv.w;
            if (OBF16) {
                __hip_bfloat16* Cb = (__hip_bfloat16*)Cv;
                __hip_bfloat162 lo = __float22bfloat162_rn(make_float2(o0, o1));
                __hip_bfloat162 hi = __float22bfloat162_rn(make_float2(o2, o3));
                *(__hip_bfloat162*)(Cb + (size_t)rr * 64 + tx * 4) = lo;
                *(__hip_bfloat162*)(Cb + (size_t)rr * 64 + tx * 4 + 2) = hi;
            } else {
                float* C = (float*)Cv;
                *(float4*)(C + (size_t)rr * 64 + tx * 4) =
                    make_float4(o0, o1, o2, o3);
            }
        }
    }
}

// ---------------------------------------------------------------------------
// Radix partition pass 1: per-block private bucket histogram (LDS only),
// written out bucket-major: cnt[bucket * NBLK_P + blk]. No global atomics.
// ---------------------------------------------------------------------------
__global__ __launch_bounds__(1024) void part_count(
    const int* __restrict__ ei1, const int* __restrict__ ei2,
    const int* __restrict__ ei3, int* __restrict__ cnt)
{
    __shared__ int lc[NBK];
    const int t = threadIdx.x;
    for (int j = t; j < NBK; j += 1024) lc[j] = 0;
    __syncthreads();

    const int chunk = (3 * EE + NBLK_P - 1) / NBLK_P;
    const int b0 = blockIdx.x * chunk;
    int b1 = b0 + chunk;
    if (b1 > 3 * EE) b1 = 3 * EE;

    for (int i = b0 + t; i < b1; i += 1024) {
        int s = i / EE;
        int e = i - s * EE;
        const int* ei = (s == 0) ? ei1 : (s == 1) ? ei2 : ei3;
        atomicAdd(&lc[s * NB + (ei[EE + e] >> 7)], 1);
    }
    __syncthreads();
    for (int j = t; j < NBK; j += 1024)
        cnt[j * NBLK_P + blockIdx.x] = lc[j];
}

// ---------------------------------------------------------------------------
// Exclusive scan over M2 counters: per-block scan + partials + add-bases.
// ---------------------------------------------------------------------------
__global__ __launch_bounds__(1024) void scan_a(
    const int* __restrict__ cnt, int* __restrict__ off,
    int* __restrict__ partials, int M)
{
    __shared__ int sh[1024];
    int t = threadIdx.x;
    int i = blockIdx.x * 1024 + t;
    int v = (i < M) ? cnt[i] : 0;
    sh[t] = v;
    __syncthreads();
    #pragma unroll
    for (int o = 1; o < 1024; o <<= 1) {
        int add = (t >= o) ? sh[t - o] : 0;
        __syncthreads();
        sh[t] += add;
        __syncthreads();
    }
    if (i < M) off[i] = sh[t] - v;
    if (t == 1023) partials[blockIdx.x] = sh[1023];
}

__global__ __launch_bounds__(512) void scan_b(int* __restrict__ partials, int P)
{
    __shared__ int sh[512];
    int t = threadIdx.x;
    int v = (t < P) ? partials[t] : 0;
    sh[t] = v;
    __syncthreads();
    #pragma unroll
    for (int o = 1; o < 512; o <<= 1) {
        int add = (t >= o) ? sh[t - o] : 0;
        __syncthreads();
        sh[t] += add;
        __syncthreads();
    }
    if (t < P) partials[t] = sh[t] - v;
}

// add block bases; extract per-bucket segment starts into off_b
__global__ __launch_bounds__(256) void scan_c(
    int* __restrict__ off, int* __restrict__ off_b,
    const int* __restrict__ partials, int M)
{
    int i = blockIdx.x * 256 + threadIdx.x;
    if (i < M) {
        int v = off[i] + partials[i >> 10];
        off[i] = v;
        if ((i & (NBLK_P - 1)) == 0) off_b[i / NBLK_P] = v;
    }
    if (i == 0) off_b[NBK] = 3 * EE;
}

// ---------------------------------------------------------------------------
// Radix partition pass 2: re-walk the same edge range; place records via LDS
// cursors (base from scanned cnt). record = (src | dst_local<<17, weight).
// ---------------------------------------------------------------------------
__global__ __launch_bounds__(1024) void part_scatter(
    const int* __restrict__ ei1, const float* __restrict__ ea1,
    const int* __restrict__ ei2, const float* __restrict__ ea2,
    const int* __restrict__ ei3, const float* __restrict__ ea3,
    const int* __restrict__ offp, int2* __restrict__ brec)
{
    __shared__ int lcur[NBK];
    const int t = threadIdx.x;
    for (int j = t; j < NBK; j += 1024)
        lcur[j] = offp[j * NBLK_P + blockIdx.x];
    __syncthreads();

    const int chunk = (3 * EE + NBLK_P - 1) / NBLK_P;
    const int b0 = blockIdx.x * chunk;
    int b1 = b0 + chunk;
    if (b1 > 3 * EE) b1 = 3 * EE;

    for (int i = b0 + t; i < b1; i += 1024) {
        int s = i / EE;
        int e = i - s * EE;
        const int* ei = (s == 0) ? ei1 : (s == 1) ? ei2 : ei3;
        const float* ea = (s == 0) ? ea1 : (s == 1) ? ea2 : ea3;
        int src = ei[e];
        int dst = ei[EE + e];
        float w = ea[e];
        int pos = atomicAdd(&lcur[s * NB + (dst >> 7)], 1);
        brec[pos] = make_int2(src | ((dst & 127) << 17), __float_as_int(w));
    }
}

// ---------------------------------------------------------------------------
// Bucket refine: one block per bucket; LDS counting sort of 128 local dsts.
// ---------------------------------------------------------------------------
__global__ __launch_bounds__(256) void bucket_refine(
    const int2* __restrict__ brec,
    const int* __restrict__ off_b,      // [NBK+1]
    int* __restrict__ node_off,         // [3N+1]
    int2* __restrict__ pairs)
{
    __shared__ int hist[128];
    __shared__ int curls[128];
    const int t = threadIdx.x;
    const int bk = blockIdx.x;
    const int s = bk / NB;
    const int b = bk - s * NB;
    const int n0 = b << 7;
    const int beg = off_b[bk];
    const int end = off_b[bk + 1];

    if (bk == 0 && t == 0) node_off[3 * NN] = 3 * EE;
    if (t < 128) hist[t] = 0;
    __syncthreads();

    for (int p = beg + t; p < end; p += 256)
        atomicAdd(&hist[(brec[p].x >> 17) & 127], 1);
    __syncthreads();

    int cnt = (t < 128) ? hist[t] : 0;
    #pragma unroll
    for (int o = 1; o < 128; o <<= 1) {
        int add = (t < 128 && t >= o) ? hist[t - o] : 0;
        __syncthreads();
        if (t < 128) hist[t] += add;
        __syncthreads();
    }
    if (t < 128) {
        int excl = beg + hist[t] - cnt;
        curls[t] = excl;
        if (n0 + t < NN) node_off[s * NN + n0 + t] = excl;
    }
    __syncthreads();

    for (int p = beg + t; p < end; p += 256) {
        int2 r = brec[p];
        int pos = atomicAdd(&curls[(r.x >> 17) & 127], 1);
        pairs[pos] = make_int2(r.x & 0x1FFFF, r.y);
    }
}

// ---------------------------------------------------------------------------
// Segmented gather (bf16 h): one wave per (node, scale); lane = column;
// 8-deep ILP.
// ---------------------------------------------------------------------------
__global__ __launch_bounds__(256) void ufg_gather(
    const __hip_bfloat16* __restrict__ h,   // [N][64] bf16
    const int* __restrict__ off,            // [3N+1]
    const int2* __restrict__ pairs,         // [3E]
    const float* __restrict__ f1, const float* __restrict__ f2,
    const float* __restrict__ f3,
    float* __restrict__ agg)                // [N][192]
{
    const int lane = threadIdx.x & 63;
    const int wid = blockIdx.x * 4 + (threadIdx.x >> 6);
    if (wid >= 3 * NN) return;
    const int s = wid / NN;
    const int n = wid - s * NN;

    const float* fp = (s == 0) ? f1 : (s == 1) ? f2 : f3;
    const float fv = fp[lane];
    const __hip_bfloat16* hl = h + lane;

    const int beg = off[wid];
    const int end = off[wid + 1];

    float acc0 = 0.f, acc1 = 0.f;
    int p = beg;

    for (; p + 8 <= end; p += 8) {
        int2 q0 = pairs[p + 0];
        int2 q1 = pairs[p + 1];
        int2 q2 = pairs[p + 2];
        int2 q3 = pairs[p + 3];
        int2 q4 = pairs[p + 4];
        int2 q5 = pairs[p + 5];
        int2 q6 = pairs[p + 6];
        int2 q7 = pairs[p + 7];
        float v0 = __bfloat162float(hl[(size_t)q0.x * 64]);
        float v1 = __bfloat162float(hl[(size_t)q1.x * 64]);
        float v2 = __bfloat162float(hl[(size_t)q2.x * 64]);
        float v3 = __bfloat162float(hl[(size_t)q3.x * 64]);
        float v4 = __bfloat162float(hl[(size_t)q4.x * 64]);
        float v5 = __bfloat162float(hl[(size_t)q5.x * 64]);
        float v6 = __bfloat162float(hl[(size_t)q6.x * 64]);
        float v7 = __bfloat162float(hl[(size_t)q7.x * 64]);
        acc0 = fmaf(__int_as_float(q0.y), v0, acc0);
        acc1 = fmaf(__int_as_float(q1.y), v1, acc1);
        acc0 = fmaf(__int_as_float(q2.y), v2, acc0);
        acc1 = fmaf(__int_as_float(q3.y), v3, acc1);
        acc0 = fmaf(__int_as_float(q4.y), v4, acc0);
        acc1 = fmaf(__int_as_float(q5.y), v5, acc1);
        acc0 = fmaf(__int_as_float(q6.y), v6, acc0);
        acc1 = fmaf(__int_as_float(q7.y), v7, acc1);
    }
    if (p + 4 <= end) {
        int2 q0 = pairs[p + 0];
        int2 q1 = pairs[p + 1];
        int2 q2 = pairs[p + 2];
        int2 q3 = pairs[p + 3];
        float v0 = __bfloat162float(hl[(size_t)q0.x * 64]);
        float v1 = __bfloat162float(hl[(size_t)q1.x * 64]);
        float v2 = __bfloat162float(hl[(size_t)q2.x * 64]);
        float v3 = __bfloat162float(hl[(size_t)q3.x * 64]);
        acc0 = fmaf(__int_as_float(q0.y), v0, acc0);
        acc1 = fmaf(__int_as_float(q1.y), v1, acc1);
        acc0 = fmaf(__int_as_float(q2.y), v2, acc0);
        acc1 = fmaf(__int_as_float(q3.y), v3, acc1);
        p += 4;
    }
    if (p + 2 <= end) {
        int2 q0 = pairs[p + 0];
        int2 q1 = pairs[p + 1];
        float v0 = __bfloat162float(hl[(size_t)q0.x * 64]);
        float v1 = __bfloat162float(hl[(size_t)q1.x * 64]);
        acc0 = fmaf(__int_as_float(q0.y), v0, acc0);
        acc1 = fmaf(__int_as_float(q1.y), v1, acc1);
        p += 2;
    }
    if (p < end) {
        int2 q = pairs[p];
        acc0 = fmaf(__int_as_float(q.y),
                    __bfloat162float(hl[(size_t)q.x * 64]), acc0);
    }

    agg[(size_t)n * 192 + s * 64 + lane] = (acc0 + acc1) * fv;
}

// ---------------------------------------------------------------------------
// mlp1 + log_softmax, tiled: 64 rows x 40 cols (padded to 64) per block.
// GEMM: relu(A[N][192]) @ W[192][40] + bias. Epilogue: row-wise log_softmax
// via 16-lane shfl_xor reduction (row lives in 16 consecutive lanes x 4 regs,
// 40 = 10 threads x float4 exactly).
// ---------------------------------------------------------------------------
__global__ __launch_bounds__(256) void gemm40_softmax(
    const float* __restrict__ A,      // [N][192]
    const float* __restrict__ B,      // [192][40]
    const float* __restrict__ bias,   // [40]
    float* __restrict__ out,          // [N][40]
    int nrows)
{
    __shared__ float As[32][68];
    __shared__ float Bs[32][64];

    const int tid = threadIdx.x;
    const int tx = tid & 15;
    const int ty = tid >> 4;
    const int row0 = blockIdx.x * 64;

    float acc[4][4] = {{0.f, 0.f, 0.f, 0.f}, {0.f, 0.f, 0.f, 0.f},
                       {0.f, 0.f, 0.f, 0.f}, {0.f, 0.f, 0.f, 0.f}};

    const int r = tid >> 2;
    const int koff = (tid & 3) * 8;
    const bool rowok = (row0 + r) < nrows;

    for (int k0 = 0; k0 < 192; k0 += 32) {
        // stage A (relu fused)
        float av[8];
        const float* ap = A + (size_t)(row0 + r) * 192 + (k0 + koff);
        if (rowok) {
            float4 v0 = *(const float4*)(ap);
            float4 v1 = *(const float4*)(ap + 4);
            av[0] = v0.x; av[1] = v0.y; av[2] = v0.z; av[3] = v0.w;
            av[4] = v1.x; av[5] = v1.y; av[6] = v1.z; av[7] = v1.w;
        } else {
            #pragma unroll
            for (int j = 0; j < 8; ++j) av[j] = 0.f;
        }
        #pragma unroll
        for (int j = 0; j < 8; ++j) As[koff + j][r] = fmaxf(av[j], 0.f);

        // stage B: 32 x 64, cols >= 40 zero-padded (scalar loads, small)
        {
            int flat = tid * 8;
            int kk = flat >> 6;
            int c0 = flat & 63;
            #pragma unroll
            for (int j = 0; j < 8; ++j) {
                int c = c0 + j;
                Bs[kk][c] = (c < 40) ? B[(size_t)(k0 + kk) * 40 + c] : 0.f;
            }
        }
        __syncthreads();

        #pragma unroll
        for (int k = 0; k < 32; ++k) {
            float4 a = *(const float4*)&As[k][ty * 4];
            float4 b = *(const float4*)&Bs[k][tx * 4];
            acc[0][0] = fmaf(a.x, b.x, acc[0][0]);
            acc[0][1] = fmaf(a.x, b.y, acc[0][1]);
            acc[0][2] = fmaf(a.x, b.z, acc[0][2]);
            acc[0][3] = fmaf(a.x, b.w, acc[0][3]);
            acc[1][0] = fmaf(a.y, b.x, acc[1][0]);
            acc[1][1] = fmaf(a.y, b.y, acc[1][1]);
            acc[1][2] = fmaf(a.y, b.z, acc[1][2]);
            acc[1][3] = fmaf(a.y, b.w, acc[1][3]);
            acc[2][0] = fmaf(a.z, b.x, acc[2][0]);
            acc[2][1] = fmaf(a.z, b.y, acc[2][1]);
            acc[2][2] = fmaf(a.z, b.z, acc[2][2]);
            acc[2][3] = fmaf(a.z, b.w, acc[2][3]);
            acc[3][0] = fmaf(a.w, b.x, acc[3][0]);
            acc[3][1] = fmaf(a.w, b.y, acc[3][1]);
            acc[3][2] = fmaf(a.w, b.z, acc[3][2]);
            acc[3][3] = fmaf(a.w, b.w, acc[3][3]);
        }
        __syncthreads();
    }

    // epilogue: + bias (cols < 40), row log_softmax via 16-lane reduce
    float bv[4];
    #pragma unroll
    for (int j = 0; j < 4; ++j) {
        int c = tx * 4 + j;
        bv[j] = (c < 40) ? bias[c] : 0.f;
    }
    const bool colok = (tx < 10);   // cols tx*4..tx*4+3 all < 40

    #pragma unroll
    for (int i = 0; i < 4; ++i) {
        float v0 = colok ? acc[i][0] + bv[0] : -1e30f;
        float v1 = colok ? acc[i][1] + bv[1] : -1e30f;
        float v2 = colok ? acc[i][2] + bv[2] : -1e30f;
        float v3 = colok ? acc[i][3] + bv[3] : -1e30f;

        float mx = fmaxf(fmaxf(v0, v1), fmaxf(v2, v3));
        #pragma unroll
        for (int o = 1; o < 16; o <<= 1)
            mx = fmaxf(mx, __shfl_xor(mx, o, 64));

        float s = __expf(v0 - mx) + __expf(v1 - mx) +
                  __expf(v2 - mx) + __expf(v3 - mx);   // invalid -> exp(-huge)=0
        #pragma unroll
        for (int o = 1; o < 16; o <<= 1)
            s += __shfl_xor(s, o, 64);

        int rr = row0 + ty * 4 + i;
        if (rr < nrows && colok) {
            float ls = mx + __logf(s);
            *(float4*)(out + (size_t)rr * 40 + tx * 4) =
                make_float4(v0 - ls, v1 - ls, v2 - ls, v3 - ls);
        }
    }
}

// ---------------------------------------------------------------------------
extern "C" void kernel_launch(void* const* d_in, const int* in_sizes, int n_in,
                              void* d_out, int out_size, void* d_ws, size_t ws_size,
                              hipStream_t stream)
{
    const float* x    = (const float*)d_in[0];
    const int*   ei1  = (const int*)d_in[1];
    const float* ea1  = (const float*)d_in[2];
    const int*   ei2  = (const int*)d_in[3];
    const float* ea2  = (const float*)d_in[4];
    const int*   ei3  = (const int*)d_in[5];
    const float* ea3  = (const float*)d_in[6];
    const float* W1   = (const float*)d_in[7];
    const float* b1   = (const float*)d_in[8];
    const float* f1_1 = (const float*)d_in[9];
    const float* f2_1 = (const float*)d_in[10];
    const float* f1_2 = (const float*)d_in[11];
    const float* f2_2 = (const float*)d_in[12];
    const float* f1_3 = (const float*)d_in[13];
    const float* f2_3 = (const float*)d_in[14];
    const float* Wm2  = (const float*)d_in[15];
    const float* bm2  = (const float*)d_in[16];
    const float* Wm1  = (const float*)d_in[17];
    const float* bm1  = (const float*)d_in[18];
    float* out = (float*)d_out;

    // ws layout. brec aliases agg: brec is dead before agg's first write.
    float* agg  = (float*)d_ws;                              // N*192 f32
    int2*  brec = (int2*)d_ws;                               // 3E int2 (alias)
    char*  base = (char*)d_ws + (size_t)NN * 192 * 4;
    __hip_bfloat16* hbuf = (__hip_bfloat16*)base;            // N*64 bf16
    int*   cnt  = (int*)(base + (size_t)NN * 64 * 2);        // M2
    int*   offp = cnt + M2;                                  // M2
    int*   part = offp + M2;                                 // 512
    int*   off_b = part + 512;                               // NBK+1 (+pad)
    int*   node_off = off_b + NBK + 2;                       // 3N+1 (+pad)
    int2*  pairs = (int2*)(node_off + 3 * NN + 2);           // 3E int2

    const int gemm_grid = (NN + 63) / 64;
    const int P = (M2 + 1023) / 1024;    // 294

    // ---- dst-sort edges: atomic-free radix partition + per-bucket refine
    part_count<<<NBLK_P, 1024, 0, stream>>>(ei1, ei2, ei3, cnt);
    scan_a<<<P, 1024, 0, stream>>>(cnt, offp, part, M2);
    scan_b<<<1, 512, 0, stream>>>(part, P);
    scan_c<<<(M2 + 255) / 256, 256, 0, stream>>>(offp, off_b, part, M2);
    part_scatter<<<NBLK_P, 1024, 0, stream>>>(ei1, ea1, ei2, ea2, ei3, ea3,
                                              offp, brec);
    bucket_refine<<<NBK, 256, 0, stream>>>(brec, off_b, node_off, pairs);

    // ---- block 1 ----
    gemm_n64<FF, false, true><<<gemm_grid, 256, 0, stream>>>(x, W1, b1,
                                                             hbuf, NN);
    ufg_gather<<<(3 * NN + 3) / 4, 256, 0, stream>>>(hbuf, node_off, pairs,
                                                     f1_1, f1_2, f1_3, agg);
    gemm_n64<192, true, true><<<gemm_grid, 256, 0, stream>>>(agg, Wm2, bm2,
                                                             hbuf, NN);

    // ---- block 2 ----
    ufg_gather<<<(3 * NN + 3) / 4, 256, 0, stream>>>(hbuf, node_off, pairs,
                                                     f2_1, f2_2, f2_3, agg);
    gemm40_softmax<<<gemm_grid, 256, 0, stream>>>(agg, Wm1, bm1, out, NN);
}